// Round 12
// baseline (159.063 us; speedup 1.0000x reference)
//
#include <hip/hip_runtime.h>
#include <math.h>

#define BATCH 32768
#define NCH   2048
#define NCH4  512                       // f32x4 per row
#define CS_BLOCKS 1024
#define RPB   (BATCH / CS_BLOCKS)       // 32 rows per colsum block
#define GATE_BLOCKS 2048
#define WS    (2 * GATE_BLOCKS * 256)   // 1048576 f32x4 window stride (2-wide)
#define NWIN  16                        // 16.7M f32x4 / WS

typedef float f32x4 __attribute__((ext_vector_type(4)));

// ---------------------------------------------------------------------------
// Pass 1 (R4-proven, unchanged): per-block partial column sums. Block b reads
// rows [b*32, b*32+32); thread t owns f32x4 quads t / t+256; plain stores of
// the partial row into d_out scratch (gate fully overwrites d_out later).
// 276 MB @ ~7.1 TB/s — at the read ceiling.
// ---------------------------------------------------------------------------
__global__ __launch_bounds__(256) void colsum_kernel(const float* __restrict__ x,
                                                     float* __restrict__ partial) {
    const int t = threadIdx.x;
    const f32x4* __restrict__ x4 = (const f32x4*)x;
    size_t base = (size_t)blockIdx.x * (RPB * NCH4) + t;

    f32x4 a0 = {0.f, 0.f, 0.f, 0.f};
    f32x4 a1 = {0.f, 0.f, 0.f, 0.f};

    #pragma unroll 4
    for (int r = 0; r < RPB; ++r) {
        a0 += x4[base];
        a1 += x4[base + 256];
        base += NCH4;
    }

    f32x4* p4 = (f32x4*)partial;
    p4[(size_t)blockIdx.x * NCH4 + t]       = a0;
    p4[(size_t)blockIdx.x * NCH4 + 256 + t] = a1;
}

// g[c] = (cos(phi-f)*0.5+0.5)^10 + rw * sin(pi*p)^2 * cos(phi) * ws,
// phi = pacc*decay + mean.
__device__ __forceinline__ float gate1(float s, float fr, float pa, float spv,
                                       float dec, float wsc, float rw) {
    float phi = pa * dec + s * (1.0f / (float)BATCH);
    float t  = cosf(phi - fr) * 0.5f + 0.5f;
    float t2 = t * t, t4 = t2 * t2, t8 = t4 * t4;
    float sp = sinf((float)M_PI * spv);
    return t8 * t2 + rw * (sp * sp * cosf(phi) * wsc);
}

// ---------------------------------------------------------------------------
// Pass 2 (R11-proven, unchanged): merged reduction + gate computation.
// 128 blocks x 256 threads; thread (slice=t>>4, ch=blk*16+(t&15)) sums 64
// partial rows with 4 accumulators; LDS tree-reduce; t<16 compute g.
// ---------------------------------------------------------------------------
__global__ __launch_bounds__(256) void gred_kernel(const float* __restrict__ partial,
                                                   const float* __restrict__ freqs,
                                                   const float* __restrict__ pdec,
                                                   const float* __restrict__ wscl,
                                                   const float* __restrict__ rwgt,
                                                   const float* __restrict__ pacc,
                                                   const float* __restrict__ spe,
                                                   float* __restrict__ g) {
    const int t = threadIdx.x;
    const int r = blockIdx.x;
    const int ch = r * 16 + (t & 15);
    const int slice = t >> 4;

    const float* pc = partial + (size_t)(slice * 64) * NCH + ch;
    float a0 = 0.f, a1 = 0.f, a2 = 0.f, a3 = 0.f;
    #pragma unroll 4
    for (int k = 0; k < 64; k += 4) {
        a0 += pc[(size_t)(k + 0) * NCH];
        a1 += pc[(size_t)(k + 1) * NCH];
        a2 += pc[(size_t)(k + 2) * NCH];
        a3 += pc[(size_t)(k + 3) * NCH];
    }

    __shared__ float sacc[256];
    sacc[t] = (a0 + a1) + (a2 + a3);
    __syncthreads();

    if (t < 16) {
        float s = 0.f;
        #pragma unroll
        for (int q = 0; q < 16; ++q)
            s += sacc[q * 16 + t];
        g[ch] = gate1(s, freqs[ch], pacc[ch], spe[ch], pdec[0], wscl[0], rwgt[0]);
    }
}

// ---------------------------------------------------------------------------
// Pass 3: out = z * (1 - exp(-|z|)), z = x * g[c].
// CHANGE vs R11: each thread owns TWO ADJACENT f32x4 (32 B) per window ->
// a wave's instruction pair covers 2 KB contiguous (was 1 KB per 8 MB jump),
// doubling the burst run length for the HBM controllers in both directions.
// Same bytes-in-flight as the proven pipeline (2 windows ahead = 64 B/thread).
// Ping-pong buffers with fully-unrolled loop -> static indexing (no scratch).
// Regular x loads, NT out stores.
// ---------------------------------------------------------------------------
__global__ __launch_bounds__(256) void gate_kernel(const float* __restrict__ x,
                                                   const float* __restrict__ g,
                                                   float* __restrict__ out) {
    const f32x4* __restrict__ x4 = (const f32x4*)x;
    const f32x4* __restrict__ g4 = (const f32x4*)g;
    f32x4* __restrict__ o4 = (f32x4*)out;

    const int tid = blockIdx.x * 256 + threadIdx.x;     // 0..524287
    const size_t i0 = 2 * (size_t)tid;                  // two adjacent f32x4

    const f32x4 gva = g4[(2 * tid)     & (NCH4 - 1)];
    const f32x4 gvb = g4[(2 * tid + 1) & (NCH4 - 1)];

#define OUTF(zv, ov)                                                  \
    do {                                                              \
        (ov).x = (zv).x * (1.0f - __expf(-fabsf((zv).x)));            \
        (ov).y = (zv).y * (1.0f - __expf(-fabsf((zv).y)));            \
        (ov).z = (zv).z * (1.0f - __expf(-fabsf((zv).z)));            \
        (ov).w = (zv).w * (1.0f - __expf(-fabsf((zv).w)));            \
    } while (0)

    f32x4 pa[2], pb[2];
    pa[0] = x4[i0];                  pb[0] = x4[i0 + 1];
    pa[1] = x4[i0 + (size_t)WS];     pb[1] = x4[i0 + (size_t)WS + 1];

    #pragma unroll
    for (int j = 0; j < NWIN; ++j) {
        f32x4 va = pa[j & 1], vb = pb[j & 1];
        if (j + 2 < NWIN) {
            pa[j & 1] = x4[i0 + (size_t)(j + 2) * WS];
            pb[j & 1] = x4[i0 + (size_t)(j + 2) * WS + 1];
        }
        f32x4 za = va * gva, zb = vb * gvb;
        f32x4 oa, ob;
        OUTF(za, oa);
        OUTF(zb, ob);
        __builtin_nontemporal_store(oa, &o4[i0 + (size_t)j * WS]);
        __builtin_nontemporal_store(ob, &o4[i0 + (size_t)j * WS + 1]);
    }
#undef OUTF
}

extern "C" void kernel_launch(void* const* d_in, const int* in_sizes, int n_in,
                              void* d_out, int out_size, void* d_ws, size_t ws_size,
                              hipStream_t stream) {
    const float* x     = (const float*)d_in[0];
    const float* freqs = (const float*)d_in[1];
    const float* pdec  = (const float*)d_in[2];
    const float* wscl  = (const float*)d_in[3];
    const float* rwgt  = (const float*)d_in[4];
    const float* pacc  = (const float*)d_in[5];
    const float* spe   = (const float*)d_in[6];
    float* out = (float*)d_out;

    float* partial = out;               // 1024*2048 floats = 8 MiB scratch in
                                        // d_out; gate fully overwrites later
    float* g = (float*)d_ws;            // 2048 floats, fully rewritten per call

    colsum_kernel<<<CS_BLOCKS, 256, 0, stream>>>(x, partial);

    gred_kernel<<<128, 256, 0, stream>>>(partial, freqs, pdec, wscl, rwgt,
                                         pacc, spe, g);

    gate_kernel<<<GATE_BLOCKS, 256, 0, stream>>>(x, g, out);
}

// Round 13
// 142.526 us; speedup vs baseline: 1.1160x; 1.1160x over previous
//
#include <hip/hip_runtime.h>
#include <math.h>

#define BATCH 32768
#define NCH   2048
#define NCH4  512                       // f32x4 per row
#define CS_BLOCKS 1024
#define RPB   (BATCH / CS_BLOCKS)       // 32 rows per colsum block
#define GATE_BLOCKS 2048
#define STRIDE (GATE_BLOCKS * 256)      // 524288 f32x4 grid stride

typedef float f32x4 __attribute__((ext_vector_type(4)));

// ---------------------------------------------------------------------------
// Pass 1 (R4-proven): per-block partial column sums. Block b reads rows
// [b*32, b*32+32) with regular loads; thread t owns f32x4 quads t / t+256
// (channels 4t..4t+3 / 1024+4t..+3); plain stores of the partial row into
// d_out scratch (gate fully overwrites d_out afterwards).
// ---------------------------------------------------------------------------
__global__ __launch_bounds__(256) void colsum_kernel(const float* __restrict__ x,
                                                     float* __restrict__ partial) {
    const int t = threadIdx.x;
    const f32x4* __restrict__ x4 = (const f32x4*)x;
    size_t base = (size_t)blockIdx.x * (RPB * NCH4) + t;

    f32x4 a0 = {0.f, 0.f, 0.f, 0.f};
    f32x4 a1 = {0.f, 0.f, 0.f, 0.f};

    #pragma unroll 4
    for (int r = 0; r < RPB; ++r) {
        a0 += x4[base];
        a1 += x4[base + 256];
        base += NCH4;
    }

    f32x4* p4 = (f32x4*)partial;
    p4[(size_t)blockIdx.x * NCH4 + t]       = a0;
    p4[(size_t)blockIdx.x * NCH4 + 256 + t] = a1;
}

// g[c] = (cos(phi-f)*0.5+0.5)^10 + rw * sin(pi*p)^2 * cos(phi) * ws,
// phi = pacc*decay + mean.
__device__ __forceinline__ float gate1(float s, float fr, float pa, float spv,
                                       float dec, float wsc, float rw) {
    float phi = pa * dec + s * (1.0f / (float)BATCH);
    float t  = cosf(phi - fr) * 0.5f + 0.5f;
    float t2 = t * t, t4 = t2 * t2, t8 = t4 * t4;
    float sp = sinf((float)M_PI * spv);
    return t8 * t2 + rw * (sp * sp * cosf(phi) * wsc);
}

// ---------------------------------------------------------------------------
// Pass 2 (R11-proven): merged reduction + gate computation.
// 128 blocks x 256 threads. Block r owns channels [r*16, r*16+16).
// Thread t: slice = t>>4, ch = r*16 + (t&15); sums 64 partial rows with 4
// independent accumulators (coalesced 64 B segments), LDS tree-reduces the
// 16 slices, threads t<16 compute g.
// ---------------------------------------------------------------------------
__global__ __launch_bounds__(256) void gred_kernel(const float* __restrict__ partial,
                                                   const float* __restrict__ freqs,
                                                   const float* __restrict__ pdec,
                                                   const float* __restrict__ wscl,
                                                   const float* __restrict__ rwgt,
                                                   const float* __restrict__ pacc,
                                                   const float* __restrict__ spe,
                                                   float* __restrict__ g) {
    const int t = threadIdx.x;
    const int r = blockIdx.x;
    const int ch = r * 16 + (t & 15);
    const int slice = t >> 4;

    const float* pc = partial + (size_t)(slice * 64) * NCH + ch;
    float a0 = 0.f, a1 = 0.f, a2 = 0.f, a3 = 0.f;
    #pragma unroll 4
    for (int k = 0; k < 64; k += 4) {
        a0 += pc[(size_t)(k + 0) * NCH];
        a1 += pc[(size_t)(k + 1) * NCH];
        a2 += pc[(size_t)(k + 2) * NCH];
        a3 += pc[(size_t)(k + 3) * NCH];
    }

    __shared__ float sacc[256];
    sacc[t] = (a0 + a1) + (a2 + a3);
    __syncthreads();

    if (t < 16) {
        float s = 0.f;
        #pragma unroll
        for (int q = 0; q < 16; ++q)
            s += sacc[q * 16 + t];
        g[ch] = gate1(s, freqs[ch], pacc[ch], spe[ch], pdec[0], wscl[0], rwgt[0]);
    }
}

// ---------------------------------------------------------------------------
// Pass 3 (R4/R11-proven, byte-identical): out = z * (1 - exp(-|z|)),
// z = x * g[c]. Regular x loads, NT out stores, 4-deep prefetch pipeline,
// one f32x4 of g per thread (channel quad fixed: tid & 511).
// ---------------------------------------------------------------------------
__global__ __launch_bounds__(256) void gate_kernel(const float* __restrict__ x,
                                                   const float* __restrict__ g,
                                                   float* __restrict__ out) {
    const f32x4* __restrict__ x4 = (const f32x4*)x;
    const f32x4* __restrict__ g4 = (const f32x4*)g;
    f32x4* __restrict__ o4 = (f32x4*)out;

    const int tid = blockIdx.x * 256 + threadIdx.x;     // 0..524287
    const f32x4 gv = g4[tid & (NCH4 - 1)];

#define EMITP(v, jj)                                                      \
    do {                                                                  \
        f32x4 z = (v) * gv;                                               \
        f32x4 o;                                                          \
        o.x = z.x * (1.0f - __expf(-fabsf(z.x)));                         \
        o.y = z.y * (1.0f - __expf(-fabsf(z.y)));                         \
        o.z = z.z * (1.0f - __expf(-fabsf(z.z)));                         \
        o.w = z.w * (1.0f - __expf(-fabsf(z.w)));                         \
        __builtin_nontemporal_store(o, &o4[tid + (size_t)(jj) * STRIDE]); \
    } while (0)

    f32x4 v0 = x4[tid + 0 * (size_t)STRIDE];
    f32x4 v1 = x4[tid + 1 * (size_t)STRIDE];
    f32x4 v2 = x4[tid + 2 * (size_t)STRIDE];
    f32x4 v3 = x4[tid + 3 * (size_t)STRIDE];

    #pragma unroll
    for (int j = 0; j < 28; j += 4) {
        f32x4 n0 = x4[tid + (size_t)(j + 4) * STRIDE];
        f32x4 n1 = x4[tid + (size_t)(j + 5) * STRIDE];
        f32x4 n2 = x4[tid + (size_t)(j + 6) * STRIDE];
        f32x4 n3 = x4[tid + (size_t)(j + 7) * STRIDE];

        EMITP(v0, j + 0); EMITP(v1, j + 1); EMITP(v2, j + 2); EMITP(v3, j + 3);

        v0 = n0; v1 = n1; v2 = n2; v3 = n3;
    }
    EMITP(v0, 28); EMITP(v1, 29); EMITP(v2, 30); EMITP(v3, 31);
#undef EMITP
}

extern "C" void kernel_launch(void* const* d_in, const int* in_sizes, int n_in,
                              void* d_out, int out_size, void* d_ws, size_t ws_size,
                              hipStream_t stream) {
    const float* x     = (const float*)d_in[0];
    const float* freqs = (const float*)d_in[1];
    const float* pdec  = (const float*)d_in[2];
    const float* wscl  = (const float*)d_in[3];
    const float* rwgt  = (const float*)d_in[4];
    const float* pacc  = (const float*)d_in[5];
    const float* spe   = (const float*)d_in[6];
    float* out = (float*)d_out;

    float* partial = out;               // 1024*2048 floats = 8 MiB scratch in
                                        // d_out; gate fully overwrites later
    float* g = (float*)d_ws;            // 2048 floats, fully rewritten per call

    // No memset needed: partial and g are fully rewritten every call, and
    // kernel-boundary cache flushes guarantee cross-dispatch visibility.
    colsum_kernel<<<CS_BLOCKS, 256, 0, stream>>>(x, partial);

    gred_kernel<<<128, 256, 0, stream>>>(partial, freqs, pdec, wscl, rwgt,
                                         pacc, spe, g);

    gate_kernel<<<GATE_BLOCKS, 256, 0, stream>>>(x, g, out);
}